// Round 2
// baseline (1464.088 us; speedup 1.0000x reference)
//
#include <hip/hip_runtime.h>
#include <hip/hip_bf16.h>
#include <math.h>

#define HW_TOT 5440
#define NQ 4096
#define DM 256

typedef __attribute__((ext_vector_type(8))) short bf16x8;
typedef __attribute__((ext_vector_type(4))) float f32x4;

__device__ inline short f2bf(float f) {
    __hip_bfloat16 h = __float2bfloat16(f);
    return *(short*)&h;
}

// ---------------------------------------------------------------------------
// GEMM: C[M,N] = A[M,K] @ W[N,K]^T + bias[N]
// ---------------------------------------------------------------------------
__global__ __launch_bounds__(256) void gemm_nt(const float* __restrict__ A,
    const float* __restrict__ W, const float* __restrict__ bias,
    float* __restrict__ C, int M, int N, int Kd)
{
    __shared__ float As[32][68];
    __shared__ float Ws[32][68];
    const int bm = blockIdx.y * 64, bn = blockIdx.x * 64;
    const int t  = threadIdx.x;
    const int tx = t & 15, ty = t >> 4;
    const int mrow = t >> 3;
    const int kcol = (t & 7) << 2;
    float acc[4][4] = {};
    for (int k0 = 0; k0 < Kd; k0 += 32) {
#pragma unroll
        for (int half = 0; half < 2; ++half) {
            int m = mrow + half * 32;
            float4 a = *(const float4*)&A[(size_t)(bm + m) * Kd + k0 + kcol];
            As[kcol + 0][m] = a.x; As[kcol + 1][m] = a.y;
            As[kcol + 2][m] = a.z; As[kcol + 3][m] = a.w;
            float4 w = *(const float4*)&W[(size_t)(bn + m) * Kd + k0 + kcol];
            Ws[kcol + 0][m] = w.x; Ws[kcol + 1][m] = w.y;
            Ws[kcol + 2][m] = w.z; Ws[kcol + 3][m] = w.w;
        }
        __syncthreads();
#pragma unroll
        for (int k = 0; k < 32; ++k) {
            float4 av = *(const float4*)&As[k][ty << 2];
            float4 wv = *(const float4*)&Ws[k][tx << 2];
            float aa[4] = {av.x, av.y, av.z, av.w};
            float ww[4] = {wv.x, wv.y, wv.z, wv.w};
#pragma unroll
            for (int i = 0; i < 4; ++i)
#pragma unroll
                for (int j = 0; j < 4; ++j) acc[i][j] += aa[i] * ww[j];
        }
        __syncthreads();
    }
#pragma unroll
    for (int i = 0; i < 4; ++i) {
        int m = bm + (ty << 2) + i;
#pragma unroll
        for (int j = 0; j < 4; ++j) {
            int n = bn + (tx << 2) + j;
            C[(size_t)m * N + n] = acc[i][j] + bias[n];
        }
    }
}

// ---------------------------------------------------------------------------
// Depthwise 3x3 conv SAME, channel-last (B,HW,256).
// ---------------------------------------------------------------------------
__global__ __launch_bounds__(256) void dwconv(const float* __restrict__ val,
    const float* __restrict__ cw, const float* __restrict__ cb,
    const int* __restrict__ shapes, const int* __restrict__ starts,
    float* __restrict__ out)
{
    __shared__ float wsm[576];
    __shared__ float bsm[64];
    const int t = threadIdx.x;
    if (t < 64) bsm[t] = cb[t];
    for (int i = t; i < 576; i += 256) wsm[i] = cw[i];
    __syncthreads();

    const int idx = blockIdx.x;
    const int b = idx / HW_TOT;
    const int pos = idx - b * HW_TOT;
    const int s1 = starts[1], s2 = starts[2], s3 = starts[3];
    const int lv = (pos >= s3) ? 3 : (pos >= s2) ? 2 : (pos >= s1) ? 1 : 0;
    const int st = (lv == 0) ? 0 : (lv == 1) ? s1 : (lv == 2) ? s2 : s3;
    const int Hh = shapes[2 * lv], Ww = shapes[2 * lv + 1];
    const int rel = pos - st;
    const int y = rel / Ww;
    const int x = rel - y * Ww;
    const int c = t;
    const int d = c & 63;
    float acc = bsm[d];
    const float* vb = val + ((size_t)(b * HW_TOT + st)) * DM + c;
#pragma unroll
    for (int ky = -1; ky <= 1; ++ky) {
        int ny = y + ky;
        if (ny < 0 || ny >= Hh) continue;
#pragma unroll
        for (int kx = -1; kx <= 1; ++kx) {
            int nx = x + kx;
            if (nx < 0 || nx >= Ww) continue;
            acc += wsm[d * 9 + (ky + 1) * 3 + (kx + 1)] * vb[(size_t)(ny * Ww + nx) * DM];
        }
    }
    out[(size_t)idx * DM + c] = acc;
}

// ---------------------------------------------------------------------------
// Fused: bilinear sampling + x_proj (MFMA) + dt_proj + selective scan (last
// step only) + LayerNorm. One wave per (b,q,k); lane = d.
// ---------------------------------------------------------------------------
__global__ __launch_bounds__(64, 4) void fused_ss(
    const float* __restrict__ conv, const float* __restrict__ offs_buf,
    const float* __restrict__ st_buf, const float* __restrict__ ref,
    const int* __restrict__ shapes, const int* __restrict__ starts,
    const float* __restrict__ xpw, const float* __restrict__ dtw,
    const float* __restrict__ dtb, const float* __restrict__ A_logs,
    const float* __restrict__ Ds, const float* __restrict__ ln_g,
    const float* __restrict__ ln_b, float* __restrict__ yout)
{
    const int wid = blockIdx.x;
    const int k  = wid & 3;
    const int bq = wid >> 2;              // b*NQ + q
    const int b  = bq >> 12;
    const int d  = threadIdx.x;
    const int g  = d >> 4, li = d & 15;

    // ssT: bf16, [17 samples][80 (64 d + pad)] rows 160B each (16B-aligned)
    __shared__ unsigned short ssT[17 * 80];
    // xdbl: f32, [l(17)][c(36)]  c: 0..3 dts, 4..19 Bs, 20..35 Cs (l=16 only)
    __shared__ float xdbl[17 * 36];

    int sh[8], stt[4];
#pragma unroll
    for (int i = 0; i < 8; ++i) sh[i] = shapes[i];
#pragma unroll
    for (int i = 0; i < 4; ++i) stt[i] = starts[i];

    const float* offp = offs_buf + (size_t)bq * 128 + k * 32;
    const float* refp = ref + (size_t)bq * 8;

    float ss[17];
#pragma unroll
    for (int s = 0; s < 16; ++s) {
        const int lv = s >> 2;
        const int Hh = sh[2 * lv], Ww = sh[2 * lv + 1];
        float gx = refp[2 * lv + 0] * (float)Ww + offp[2 * s + 0] - 0.5f;
        float gy = refp[2 * lv + 1] * (float)Hh + offp[2 * s + 1] - 0.5f;
        float x0f = floorf(gx), y0f = floorf(gy);
        int ix0 = (int)x0f, iy0 = (int)y0f;
        float wx = gx - x0f, wy = gy - y0f;
        const float* base = conv + ((size_t)(b * HW_TOT + stt[lv])) * DM + k * 64 + d;
        float acc = 0.f;
        bool vx0 = (ix0 >= 0) & (ix0 < Ww);
        bool vx1 = (ix0 + 1 >= 0) & (ix0 + 1 < Ww);
        if (iy0 >= 0 && iy0 < Hh) {
            const float* r0 = base + (size_t)iy0 * Ww * DM;
            if (vx0) acc += (1.f - wx) * (1.f - wy) * r0[(size_t)ix0 * DM];
            if (vx1) acc += wx * (1.f - wy) * r0[(size_t)(ix0 + 1) * DM];
        }
        if (iy0 + 1 >= 0 && iy0 + 1 < Hh) {
            const float* r1 = base + (size_t)(iy0 + 1) * Ww * DM;
            if (vx0) acc += (1.f - wx) * wy * r1[(size_t)ix0 * DM];
            if (vx1) acc += wx * wy * r1[(size_t)(ix0 + 1) * DM];
        }
        ss[s] = acc;
        ssT[s * 80 + d] = (unsigned short)f2bf(acc);
    }
    ss[16] = st_buf[(size_t)bq * 256 + k * 64 + d];
    ssT[16 * 80 + d] = (unsigned short)f2bf(ss[16]);
    __syncthreads();   // 1-wave block: cheap; orders ssT writes before reads

    // ---- x_dbl via MFMA: out[36][17] = xpw_k[36][64] @ ss[64][17] ----
    // B fragments: B[kd][col], slot (g,j) -> kd = kt*32+g*8+j, col = nt*16+li
    bf16x8 bfrag[2][2];
#pragma unroll
    for (int kt = 0; kt < 2; ++kt)
#pragma unroll
        for (int nt = 0; nt < 2; ++nt) {
            int col = nt * 16 + li; if (col > 16) col = 16;   // clamp: cols>16 unused
            bfrag[kt][nt] = *(const bf16x8*)&ssT[col * 80 + kt * 32 + g * 8];
        }
    // A fragments: A[c][kd], slot (g,j) -> c = mt*16+li, kd = kt*32+g*8+j
    bf16x8 afrag[3][2];
    const float* xpk = xpw + k * 36 * 64;
#pragma unroll
    for (int mt = 0; mt < 3; ++mt) {
        int c = mt * 16 + li;
#pragma unroll
        for (int kt = 0; kt < 2; ++kt) {
            bf16x8 a;
            if (c < 36) {
                const float* p = xpk + c * 64 + kt * 32 + g * 8;
                f32x4 v0 = *(const f32x4*)p;
                f32x4 v1 = *(const f32x4*)(p + 4);
#pragma unroll
                for (int j = 0; j < 4; ++j) { a[j] = f2bf(v0[j]); a[4 + j] = f2bf(v1[j]); }
            } else {
#pragma unroll
                for (int j = 0; j < 8; ++j) a[j] = 0;
            }
            afrag[mt][kt] = a;
        }
    }
#pragma unroll
    for (int mt = 0; mt < 3; ++mt)
#pragma unroll
        for (int nt = 0; nt < 2; ++nt) {
            f32x4 acc = {0.f, 0.f, 0.f, 0.f};
#pragma unroll
            for (int kt = 0; kt < 2; ++kt)
                acc = __builtin_amdgcn_mfma_f32_16x16x32_bf16(afrag[mt][kt], bfrag[kt][nt], acc, 0, 0, 0);
            // C/D: col = lane&15 (+nt*16), row c = (lane>>4)*4 + r (+mt*16)
            int colD = nt * 16 + li;
            if (colD <= 16) {
                int rbase = mt * 16 + g * 4;
#pragma unroll
                for (int r = 0; r < 4; ++r) {
                    int c = rbase + r;
                    if (c < 36) xdbl[colD * 36 + c] = acc[r];
                }
            }
        }
    __syncthreads();

    // ---- selective scan (per-lane d), final C.h only ----
    const int kd = k * 64 + d;
    float Avals[16];
    const float* Ap = A_logs + (size_t)kd * 16;
#pragma unroll
    for (int n = 0; n < 16; ++n) Avals[n] = -__expf(Ap[n]);
    float dtwr[4];
#pragma unroll
    for (int r = 0; r < 4; ++r) dtwr[r] = dtw[kd * 4 + r];
    const float dtbv = dtb[kd];
    float h[16];
#pragma unroll
    for (int n = 0; n < 16; ++n) h[n] = 0.f;
#pragma unroll
    for (int t = 0; t < 17; ++t) {
        f32x4 dt4 = *(const f32x4*)&xdbl[t * 36 + 0];
        f32x4 b0  = *(const f32x4*)&xdbl[t * 36 + 4];
        f32x4 b1  = *(const f32x4*)&xdbl[t * 36 + 8];
        f32x4 b2  = *(const f32x4*)&xdbl[t * 36 + 12];
        f32x4 b3  = *(const f32x4*)&xdbl[t * 36 + 16];
        float xv = dtwr[0] * dt4[0] + dtwr[1] * dt4[1]
                 + dtwr[2] * dt4[2] + dtwr[3] * dt4[3] + dtbv;
        float delta = (xv > 20.f) ? xv : log1pf(__expf(xv));
        float du = delta * ss[t];
        float Bv[16] = {b0[0], b0[1], b0[2], b0[3], b1[0], b1[1], b1[2], b1[3],
                        b2[0], b2[1], b2[2], b2[3], b3[0], b3[1], b3[2], b3[3]};
#pragma unroll
        for (int n = 0; n < 16; ++n)
            h[n] = __expf(delta * Avals[n]) * h[n] + du * Bv[n];
    }
    f32x4 c0 = *(const f32x4*)&xdbl[16 * 36 + 20];
    f32x4 c1 = *(const f32x4*)&xdbl[16 * 36 + 24];
    f32x4 c2 = *(const f32x4*)&xdbl[16 * 36 + 28];
    f32x4 c3 = *(const f32x4*)&xdbl[16 * 36 + 32];
    float Cv[16] = {c0[0], c0[1], c0[2], c0[3], c1[0], c1[1], c1[2], c1[3],
                    c2[0], c2[1], c2[2], c2[3], c3[0], c3[1], c3[2], c3[3]};
    float yv = 0.f;
#pragma unroll
    for (int n = 0; n < 16; ++n) yv += h[n] * Cv[n];
    yv += ss[16] * Ds[kd];

    // LayerNorm over the 64 lanes (d dimension)
    float mu = yv;
#pragma unroll
    for (int off = 32; off; off >>= 1) mu += __shfl_xor(mu, off);
    mu *= (1.f / 64.f);
    float dv = yv - mu;
    float var = dv * dv;
#pragma unroll
    for (int off = 32; off; off >>= 1) var += __shfl_xor(var, off);
    var *= (1.f / 64.f);
    float o = dv / sqrtf(var + 1e-5f) * ln_g[d] + ln_b[d];
    yout[(size_t)bq * 256 + kd] = o;
}

// ---------------------------------------------------------------------------
extern "C" void kernel_launch(void* const* d_in, const int* in_sizes, int n_in,
                              void* d_out, int out_size, void* d_ws, size_t ws_size,
                              hipStream_t stream)
{
    const float* query   = (const float*)d_in[0];
    const float* refpts  = (const float*)d_in[1];
    const float* inflat  = (const float*)d_in[2];
    const int*   shapes  = (const int*)d_in[3];
    const int*   starts  = (const int*)d_in[4];
    const float* W_value = (const float*)d_in[5];
    const float* b_value = (const float*)d_in[6];
    const float* W_offs  = (const float*)d_in[7];
    const float* b_offs  = (const float*)d_in[8];
    const float* W_query = (const float*)d_in[9];
    const float* b_query = (const float*)d_in[10];
    const float* W_out   = (const float*)d_in[11];
    const float* b_out   = (const float*)d_in[12];
    const float* conv_w  = (const float*)d_in[13];
    const float* conv_b  = (const float*)d_in[14];
    const float* xpw     = (const float*)d_in[15];
    const float* dtw     = (const float*)d_in[16];
    const float* dtb     = (const float*)d_in[17];
    const float* A_logs  = (const float*)d_in[18];
    const float* Dsp     = (const float*)d_in[19];
    const float* ln_g    = (const float*)d_in[20];
    const float* ln_b    = (const float*)d_in[21];
    float* out = (float*)d_out;

    float* value   = (float*)d_ws;
    float* convout = value   + (size_t)10880 * 256;
    float* offsb   = convout + (size_t)10880 * 256;
    float* stb     = offsb   + (size_t)8192 * 128;
    float* ybuf    = stb     + (size_t)8192 * 256;

    gemm_nt<<<dim3(256 / 64, 10880 / 64), 256, 0, stream>>>(
        inflat, W_value, b_value, value, 10880, 256, 256);
    dwconv<<<10880, 256, 0, stream>>>(value, conv_w, conv_b, shapes, starts, convout);
    gemm_nt<<<dim3(128 / 64, 8192 / 64), 256, 0, stream>>>(
        query, W_offs, b_offs, offsb, 8192, 128, 256);
    gemm_nt<<<dim3(256 / 64, 8192 / 64), 256, 0, stream>>>(
        query, W_query, b_query, stb, 8192, 256, 256);
    fused_ss<<<32768, 64, 0, stream>>>(convout, offsb, stb, refpts, shapes, starts,
                                       xpw, dtw, dtb, A_logs, Dsp, ln_g, ln_b, ybuf);
    gemm_nt<<<dim3(256 / 64, 8192 / 64), 256, 0, stream>>>(
        ybuf, W_out, b_out, out, 8192, 256, 256);
}

// Round 3
// 747.563 us; speedup vs baseline: 1.9585x; 1.9585x over previous
//
#include <hip/hip_runtime.h>
#include <hip/hip_bf16.h>
#include <math.h>

#define HW_TOT 5440
#define NQ 4096
#define DM 256

typedef __attribute__((ext_vector_type(8))) short bf16x8;
typedef __attribute__((ext_vector_type(4))) float f32x4;

__device__ inline short f2bf(float f) {
    __hip_bfloat16 h = __float2bfloat16(f);
    return *(short*)&h;
}

// ---------------------------------------------------------------------------
// GEMM: C[M,N] = A[M,K] @ W[N,K]^T + bias[N]
// ---------------------------------------------------------------------------
__global__ __launch_bounds__(256) void gemm_nt(const float* __restrict__ A,
    const float* __restrict__ W, const float* __restrict__ bias,
    float* __restrict__ C, int M, int N, int Kd)
{
    __shared__ float As[32][68];
    __shared__ float Ws[32][68];
    const int bm = blockIdx.y * 64, bn = blockIdx.x * 64;
    const int t  = threadIdx.x;
    const int tx = t & 15, ty = t >> 4;
    const int mrow = t >> 3;
    const int kcol = (t & 7) << 2;
    float acc[4][4] = {};
    for (int k0 = 0; k0 < Kd; k0 += 32) {
#pragma unroll
        for (int half = 0; half < 2; ++half) {
            int m = mrow + half * 32;
            float4 a = *(const float4*)&A[(size_t)(bm + m) * Kd + k0 + kcol];
            As[kcol + 0][m] = a.x; As[kcol + 1][m] = a.y;
            As[kcol + 2][m] = a.z; As[kcol + 3][m] = a.w;
            float4 w = *(const float4*)&W[(size_t)(bn + m) * Kd + k0 + kcol];
            Ws[kcol + 0][m] = w.x; Ws[kcol + 1][m] = w.y;
            Ws[kcol + 2][m] = w.z; Ws[kcol + 3][m] = w.w;
        }
        __syncthreads();
#pragma unroll
        for (int k = 0; k < 32; ++k) {
            float4 av = *(const float4*)&As[k][ty << 2];
            float4 wv = *(const float4*)&Ws[k][tx << 2];
            float aa[4] = {av.x, av.y, av.z, av.w};
            float ww[4] = {wv.x, wv.y, wv.z, wv.w};
#pragma unroll
            for (int i = 0; i < 4; ++i)
#pragma unroll
                for (int j = 0; j < 4; ++j) acc[i][j] += aa[i] * ww[j];
        }
        __syncthreads();
    }
#pragma unroll
    for (int i = 0; i < 4; ++i) {
        int m = bm + (ty << 2) + i;
#pragma unroll
        for (int j = 0; j < 4; ++j) {
            int n = bn + (tx << 2) + j;
            C[(size_t)m * N + n] = acc[i][j] + bias[n];
        }
    }
}

// ---------------------------------------------------------------------------
// Depthwise 3x3 conv SAME, channel-last (B,HW,256).
// ---------------------------------------------------------------------------
__global__ __launch_bounds__(256) void dwconv(const float* __restrict__ val,
    const float* __restrict__ cw, const float* __restrict__ cb,
    const int* __restrict__ shapes, const int* __restrict__ starts,
    float* __restrict__ out)
{
    __shared__ float wsm[576];
    __shared__ float bsm[64];
    const int t = threadIdx.x;
    if (t < 64) bsm[t] = cb[t];
    for (int i = t; i < 576; i += 256) wsm[i] = cw[i];
    __syncthreads();

    const int idx = blockIdx.x;
    const int b = idx / HW_TOT;
    const int pos = idx - b * HW_TOT;
    const int s1 = starts[1], s2 = starts[2], s3 = starts[3];
    const int lv = (pos >= s3) ? 3 : (pos >= s2) ? 2 : (pos >= s1) ? 1 : 0;
    const int st = (lv == 0) ? 0 : (lv == 1) ? s1 : (lv == 2) ? s2 : s3;
    const int Hh = shapes[2 * lv], Ww = shapes[2 * lv + 1];
    const int rel = pos - st;
    const int y = rel / Ww;
    const int x = rel - y * Ww;
    const int c = t;
    const int d = c & 63;
    float acc = bsm[d];
    const float* vb = val + ((size_t)(b * HW_TOT + st)) * DM + c;
#pragma unroll
    for (int ky = -1; ky <= 1; ++ky) {
        int ny = y + ky;
        if (ny < 0 || ny >= Hh) continue;
#pragma unroll
        for (int kx = -1; kx <= 1; ++kx) {
            int nx = x + kx;
            if (nx < 0 || nx >= Ww) continue;
            acc += wsm[d * 9 + (ky + 1) * 3 + (kx + 1)] * vb[(size_t)(ny * Ww + nx) * DM];
        }
    }
    out[(size_t)idx * DM + c] = acc;
}

// ---------------------------------------------------------------------------
// Prep: xpw -> bf16 (same [k][36][64] layout), aneg = -exp(A_logs).
// ---------------------------------------------------------------------------
__global__ __launch_bounds__(256) void prep(const float* __restrict__ xpw,
    const float* __restrict__ A_logs, unsigned short* __restrict__ xpwb,
    float* __restrict__ aneg)
{
    int i = blockIdx.x * 256 + threadIdx.x;
    if (i < 9216) xpwb[i] = (unsigned short)f2bf(xpw[i]);
    if (i < 4096) aneg[i] = -__expf(A_logs[i]);
}

// ---------------------------------------------------------------------------
// Fused: bilinear sampling + x_proj (MFMA) + dt_proj + selective scan (last
// step only) + LayerNorm. One wave per (b,q,k); lane = d.
// ---------------------------------------------------------------------------
__global__ __launch_bounds__(64) void fused_ss(
    const float* __restrict__ conv, const float* __restrict__ offs_buf,
    const float* __restrict__ st_buf, const float* __restrict__ ref,
    const int* __restrict__ shapes, const int* __restrict__ starts,
    const unsigned short* __restrict__ xpwb, const float* __restrict__ dtw,
    const float* __restrict__ dtb, const float* __restrict__ aneg,
    const float* __restrict__ Ds, const float* __restrict__ ln_g,
    const float* __restrict__ ln_b, float* __restrict__ yout)
{
    const int wid = blockIdx.x;
    const int k  = wid & 3;
    const int bq = wid >> 2;              // b*NQ + q
    const int b  = bq >> 12;
    const int d  = threadIdx.x;
    const int g  = d >> 4, li = d & 15;

    // ssT: bf16, [17 samples][80 (64 d + pad)] rows 160B each (16B-aligned)
    __shared__ unsigned short ssT[17 * 80];
    // xdbl: f32, [l(17)][c(36)]  c: 0..3 dts, 4..19 Bs, 20..35 Cs (l=16 only)
    __shared__ float xdbl[17 * 36];

    int sh[8], stt[4];
#pragma unroll
    for (int i = 0; i < 8; ++i) sh[i] = shapes[i];
#pragma unroll
    for (int i = 0; i < 4; ++i) stt[i] = starts[i];

    const float* offp = offs_buf + (size_t)bq * 128 + k * 32;
    const float* refp = ref + (size_t)bq * 8;

    float ss[17];
#pragma unroll
    for (int s = 0; s < 16; ++s) {
        const int lv = s >> 2;
        const int Hh = sh[2 * lv], Ww = sh[2 * lv + 1];
        float gx = refp[2 * lv + 0] * (float)Ww + offp[2 * s + 0] - 0.5f;
        float gy = refp[2 * lv + 1] * (float)Hh + offp[2 * s + 1] - 0.5f;
        float x0f = floorf(gx), y0f = floorf(gy);
        int ix0 = (int)x0f, iy0 = (int)y0f;
        float wx = gx - x0f, wy = gy - y0f;
        const float* base = conv + ((size_t)(b * HW_TOT + stt[lv])) * DM + k * 64 + d;
        float acc = 0.f;
        bool vx0 = (ix0 >= 0) & (ix0 < Ww);
        bool vx1 = (ix0 + 1 >= 0) & (ix0 + 1 < Ww);
        if (iy0 >= 0 && iy0 < Hh) {
            const float* r0 = base + (size_t)iy0 * Ww * DM;
            if (vx0) acc += (1.f - wx) * (1.f - wy) * r0[(size_t)ix0 * DM];
            if (vx1) acc += wx * (1.f - wy) * r0[(size_t)(ix0 + 1) * DM];
        }
        if (iy0 + 1 >= 0 && iy0 + 1 < Hh) {
            const float* r1 = base + (size_t)(iy0 + 1) * Ww * DM;
            if (vx0) acc += (1.f - wx) * wy * r1[(size_t)ix0 * DM];
            if (vx1) acc += wx * wy * r1[(size_t)(ix0 + 1) * DM];
        }
        ss[s] = acc;
        ssT[s * 80 + d] = (unsigned short)f2bf(acc);
    }
    ss[16] = st_buf[(size_t)bq * 256 + k * 64 + d];
    ssT[16 * 80 + d] = (unsigned short)f2bf(ss[16]);
    __syncthreads();   // 1-wave block: orders ssT writes before reads

    // ---- x_dbl via MFMA: out[36][17] = xpw_k[36][64] @ ss[64][17] ----
    // B fragments: B[kd][col], slot (g,j) -> kd = kt*32+g*8+j, col = nt*16+li
    bf16x8 bfrag[2][2];
#pragma unroll
    for (int kt = 0; kt < 2; ++kt)
#pragma unroll
        for (int nt = 0; nt < 2; ++nt) {
            int col = nt * 16 + li; if (col > 16) col = 16;   // cols>16 unused
            bfrag[kt][nt] = *(const bf16x8*)&ssT[col * 80 + kt * 32 + g * 8];
        }
    const unsigned short* xpk = xpwb + k * 36 * 64;
#pragma unroll
    for (int mt = 0; mt < 3; ++mt) {
        // A fragments: A[c][kd], slot (g,j) -> c = mt*16+li, kd = kt*32+g*8+j
        int c = mt * 16 + li;
        bf16x8 afrag[2];
#pragma unroll
        for (int kt = 0; kt < 2; ++kt) {
            if (c < 36) afrag[kt] = *(const bf16x8*)&xpk[c * 64 + kt * 32 + g * 8];
            else { bf16x8 z = {0,0,0,0,0,0,0,0}; afrag[kt] = z; }
        }
#pragma unroll
        for (int nt = 0; nt < 2; ++nt) {
            f32x4 acc = {0.f, 0.f, 0.f, 0.f};
#pragma unroll
            for (int kt = 0; kt < 2; ++kt)
                acc = __builtin_amdgcn_mfma_f32_16x16x32_bf16(afrag[kt], bfrag[kt][nt], acc, 0, 0, 0);
            // C/D: col = lane&15 (+nt*16), row c = (lane>>4)*4 + r (+mt*16)
            int colD = nt * 16 + li;
            if (colD <= 16) {
                int rbase = mt * 16 + g * 4;
#pragma unroll
                for (int r = 0; r < 4; ++r) {
                    int cc = rbase + r;
                    if (cc < 36) xdbl[colD * 36 + cc] = acc[r];
                }
            }
        }
    }
    __syncthreads();

    // ---- selective scan (per-lane d), final C.h only ----
    const int kd = k * 64 + d;
    float Avals[16];
    {
        const float* Ap = aneg + (size_t)kd * 16;
        f32x4 a0 = *(const f32x4*)&Ap[0];
        f32x4 a1 = *(const f32x4*)&Ap[4];
        f32x4 a2 = *(const f32x4*)&Ap[8];
        f32x4 a3 = *(const f32x4*)&Ap[12];
#pragma unroll
        for (int n = 0; n < 4; ++n) {
            Avals[n] = a0[n]; Avals[4 + n] = a1[n];
            Avals[8 + n] = a2[n]; Avals[12 + n] = a3[n];
        }
    }
    float dtwr[4];
#pragma unroll
    for (int r = 0; r < 4; ++r) dtwr[r] = dtw[kd * 4 + r];
    const float dtbv = dtb[kd];
    float h[16];
#pragma unroll
    for (int n = 0; n < 16; ++n) h[n] = 0.f;
#pragma unroll
    for (int t = 0; t < 17; ++t) {
        f32x4 dt4 = *(const f32x4*)&xdbl[t * 36 + 0];
        f32x4 b0  = *(const f32x4*)&xdbl[t * 36 + 4];
        f32x4 b1  = *(const f32x4*)&xdbl[t * 36 + 8];
        f32x4 b2  = *(const f32x4*)&xdbl[t * 36 + 12];
        f32x4 b3  = *(const f32x4*)&xdbl[t * 36 + 16];
        float xv = dtwr[0] * dt4[0] + dtwr[1] * dt4[1]
                 + dtwr[2] * dt4[2] + dtwr[3] * dt4[3] + dtbv;
        float delta = (xv > 20.f) ? xv : log1pf(__expf(xv));
        float du = delta * ss[t];
        float Bv[16] = {b0[0], b0[1], b0[2], b0[3], b1[0], b1[1], b1[2], b1[3],
                        b2[0], b2[1], b2[2], b2[3], b3[0], b3[1], b3[2], b3[3]};
#pragma unroll
        for (int n = 0; n < 16; ++n)
            h[n] = __expf(delta * Avals[n]) * h[n] + du * Bv[n];
    }
    f32x4 c0 = *(const f32x4*)&xdbl[16 * 36 + 20];
    f32x4 c1 = *(const f32x4*)&xdbl[16 * 36 + 24];
    f32x4 c2 = *(const f32x4*)&xdbl[16 * 36 + 28];
    f32x4 c3 = *(const f32x4*)&xdbl[16 * 36 + 32];
    float Cv[16] = {c0[0], c0[1], c0[2], c0[3], c1[0], c1[1], c1[2], c1[3],
                    c2[0], c2[1], c2[2], c2[3], c3[0], c3[1], c3[2], c3[3]};
    float yv = 0.f;
#pragma unroll
    for (int n = 0; n < 16; ++n) yv += h[n] * Cv[n];
    yv += ss[16] * Ds[kd];

    // LayerNorm over the 64 lanes (d dimension)
    float mu = yv;
#pragma unroll
    for (int off = 32; off; off >>= 1) mu += __shfl_xor(mu, off);
    mu *= (1.f / 64.f);
    float dv = yv - mu;
    float var = dv * dv;
#pragma unroll
    for (int off = 32; off; off >>= 1) var += __shfl_xor(var, off);
    var *= (1.f / 64.f);
    float o = dv / sqrtf(var + 1e-5f) * ln_g[d] + ln_b[d];
    yout[(size_t)bq * 256 + kd] = o;
}

// ---------------------------------------------------------------------------
extern "C" void kernel_launch(void* const* d_in, const int* in_sizes, int n_in,
                              void* d_out, int out_size, void* d_ws, size_t ws_size,
                              hipStream_t stream)
{
    const float* query   = (const float*)d_in[0];
    const float* refpts  = (const float*)d_in[1];
    const float* inflat  = (const float*)d_in[2];
    const int*   shapes  = (const int*)d_in[3];
    const int*   starts  = (const int*)d_in[4];
    const float* W_value = (const float*)d_in[5];
    const float* b_value = (const float*)d_in[6];
    const float* W_offs  = (const float*)d_in[7];
    const float* b_offs  = (const float*)d_in[8];
    const float* W_query = (const float*)d_in[9];
    const float* b_query = (const float*)d_in[10];
    const float* W_out   = (const float*)d_in[11];
    const float* b_out   = (const float*)d_in[12];
    const float* conv_w  = (const float*)d_in[13];
    const float* conv_b  = (const float*)d_in[14];
    const float* xpw     = (const float*)d_in[15];
    const float* dtw     = (const float*)d_in[16];
    const float* dtb     = (const float*)d_in[17];
    const float* A_logs  = (const float*)d_in[18];
    const float* Dsp     = (const float*)d_in[19];
    const float* ln_g    = (const float*)d_in[20];
    const float* ln_b    = (const float*)d_in[21];
    float* out = (float*)d_out;

    float* value   = (float*)d_ws;
    float* convout = value   + (size_t)10880 * 256;
    float* offsb   = convout + (size_t)10880 * 256;
    float* stb     = offsb   + (size_t)8192 * 128;
    float* ybuf    = stb     + (size_t)8192 * 256;
    float* aneg    = ybuf    + (size_t)8192 * 256;
    unsigned short* xpwb = (unsigned short*)(aneg + 4096);

    prep<<<36, 256, 0, stream>>>(xpw, A_logs, xpwb, aneg);
    gemm_nt<<<dim3(256 / 64, 10880 / 64), 256, 0, stream>>>(
        inflat, W_value, b_value, value, 10880, 256, 256);
    dwconv<<<10880, 256, 0, stream>>>(value, conv_w, conv_b, shapes, starts, convout);
    gemm_nt<<<dim3(128 / 64, 8192 / 64), 256, 0, stream>>>(
        query, W_offs, b_offs, offsb, 8192, 128, 256);
    gemm_nt<<<dim3(256 / 64, 8192 / 64), 256, 0, stream>>>(
        query, W_query, b_query, stb, 8192, 256, 256);
    fused_ss<<<32768, 64, 0, stream>>>(convout, offsb, stb, refpts, shapes, starts,
                                       xpwb, dtw, dtb, aneg, Dsp, ln_g, ln_b, ybuf);
    gemm_nt<<<dim3(256 / 64, 8192 / 64), 256, 0, stream>>>(
        ybuf, W_out, b_out, out, 8192, 256, 256);
}